// Round 1
// baseline (240.540 us; speedup 1.0000x reference)
//
#include <hip/hip_runtime.h>

// dense_image_warp: B=8, H=512, W=512, C=16, fp32.
// One thread per (b,y,x,cg) where cg indexes a float4 channel group (C/4=4).
// tid bit layout: [b:3][y:9][x:9][cg:2] -> 2^23 = 8388608 threads.
// Consecutive lanes cover the 4 channel groups of one pixel, so each corner
// gather is a 64B contiguous segment and the output store is fully coalesced.

__global__ __launch_bounds__(256) void warp_kernel(
    const float* __restrict__ img,
    const float* __restrict__ flow,
    float* __restrict__ out)
{
    const int tid = blockIdx.x * blockDim.x + threadIdx.x;

    const int cg = tid & 3;
    const int x  = (tid >> 2) & 511;
    const int y  = (tid >> 11) & 511;
    const int b  = tid >> 20;

    const int pix = (((b << 9) + y) << 9) + x;   // (b*512 + y)*512 + x

    const float2 f = ((const float2*)flow)[pix];
    const float qy = (float)y - f.x;
    const float qx = (float)x - f.y;

    float fy = floorf(qy); fy = fminf(fmaxf(fy, 0.0f), 510.0f);
    float fx = floorf(qx); fx = fminf(fmaxf(fx, 0.0f), 510.0f);
    const float ay = fminf(fmaxf(qy - fy, 0.0f), 1.0f);
    const float ax = fminf(fmaxf(qx - fx, 0.0f), 1.0f);
    const int iy = (int)fy;
    const int ix = (int)fx;

    const float* p = img + ((size_t)((((b << 9) + iy) << 9) + ix)) * 16 + (cg << 2);

    const float4 tl = *(const float4*)(p);
    const float4 tr = *(const float4*)(p + 16);
    const float4 bl = *(const float4*)(p + 512 * 16);
    const float4 br = *(const float4*)(p + 512 * 16 + 16);

    float4 r;
    {
        float t, u;
        t = tl.x + ax * (tr.x - tl.x);
        u = bl.x + ax * (br.x - bl.x);
        r.x = t + ay * (u - t);
        t = tl.y + ax * (tr.y - tl.y);
        u = bl.y + ax * (br.y - bl.y);
        r.y = t + ay * (u - t);
        t = tl.z + ax * (tr.z - tl.z);
        u = bl.z + ax * (br.z - bl.z);
        r.z = t + ay * (u - t);
        t = tl.w + ax * (tr.w - tl.w);
        u = bl.w + ax * (br.w - bl.w);
        r.w = t + ay * (u - t);
    }

    ((float4*)out)[tid] = r;
}

extern "C" void kernel_launch(void* const* d_in, const int* in_sizes, int n_in,
                              void* d_out, int out_size, void* d_ws, size_t ws_size,
                              hipStream_t stream) {
    const float* img  = (const float*)d_in[0];
    const float* flow = (const float*)d_in[1];
    float* out = (float*)d_out;

    const int total = 8 * 512 * 512 * 4;   // threads (float4 granularity)
    const int block = 256;
    const int grid = total / block;        // 32768
    warp_kernel<<<grid, block, 0, stream>>>(img, flow, out);
}